// Round 1
// baseline (376.912 us; speedup 1.0000x reference)
//
#include <hip/hip_runtime.h>

constexpr int FIN = 512;
constexpr int HID = 16;
constexpr int NC  = 7;

// deg[d] += 1 for each in-edge
__global__ void k_deg(const int* __restrict__ dst, float* __restrict__ degf, int E) {
    int e = blockIdx.x * blockDim.x + threadIdx.x;
    if (e < E) atomicAdd(&degf[dst[e]], 1.0f);
}

__global__ void k_dinv(const float* __restrict__ degf, float* __restrict__ dinv, int N) {
    int i = blockIdx.x * blockDim.x + threadIdx.x;
    if (i < N) dinv[i] = rsqrtf(degf[i] + 1.0f);  // +1 = self loop
}

// g0[i] = (x[i] @ W0) * dinv[i]; s0[i] initialized to g0[i] (self-loop term).
// 2 threads per row (k-split 256+256), combine via shfl_xor(1).
__global__ void __launch_bounds__(256) k_xw0(
    const float* __restrict__ x, const float* __restrict__ W0,
    const float* __restrict__ dinv, float* __restrict__ g0,
    float* __restrict__ s0, int N) {
    __shared__ float wl[FIN * HID];  // 32 KiB
    for (int i = threadIdx.x; i < FIN * HID; i += 256) wl[i] = W0[i];
    __syncthreads();

    int t = blockIdx.x * 256 + threadIdx.x;
    int row = t >> 1, half = t & 1;
    if (row >= N) return;

    const float4* xr = (const float4*)(x + (size_t)row * FIN + half * (FIN / 2));
    const float* wbase = wl + half * (FIN / 2) * HID;

    float acc[HID];
#pragma unroll
    for (int j = 0; j < HID; ++j) acc[j] = 0.f;

#pragma unroll 4
    for (int k4 = 0; k4 < FIN / 2 / 4; ++k4) {
        float4 xv = xr[k4];
        const float* wr = wbase + k4 * 4 * HID;  // wave-uniform (2 addrs: free 2-way)
#pragma unroll
        for (int j = 0; j < HID; ++j) {
            acc[j] = fmaf(xv.x, wr[j], acc[j]);
            acc[j] = fmaf(xv.y, wr[j + HID], acc[j]);
            acc[j] = fmaf(xv.z, wr[j + 2 * HID], acc[j]);
            acc[j] = fmaf(xv.w, wr[j + 3 * HID], acc[j]);
        }
    }
#pragma unroll
    for (int j = 0; j < HID; ++j) acc[j] += __shfl_xor(acc[j], 1);

    float dv = dinv[row];
    int jb = half * 8;  // even lane writes j 0..7, odd lane j 8..15
    float4 v0, v1;
    v0.x = acc[jb + 0] * dv; v0.y = acc[jb + 1] * dv;
    v0.z = acc[jb + 2] * dv; v0.w = acc[jb + 3] * dv;
    v1.x = acc[jb + 4] * dv; v1.y = acc[jb + 5] * dv;
    v1.z = acc[jb + 6] * dv; v1.w = acc[jb + 7] * dv;
    float4* gp = (float4*)(g0 + (size_t)row * HID + jb);
    float4* sp = (float4*)(s0 + (size_t)row * HID + jb);
    gp[0] = v0; gp[1] = v1;
    sp[0] = v0; sp[1] = v1;
}

// s0[dst] += g0[src]  (one lane per (edge, j))
__global__ void k_scat0(const int* __restrict__ src, const int* __restrict__ dst,
                        const float* __restrict__ g0, float* __restrict__ s0, int E) {
    int t = blockIdx.x * 256 + threadIdx.x;
    int e = t >> 4;
    if (e >= E) return;
    int j = t & 15;
    atomicAdd(&s0[(size_t)dst[e] * HID + j], g0[(size_t)src[e] * HID + j]);
}

// h1 = relu(s0*dinv + b0); t1 = h1 @ W1; g1 = t1*dinv; out_acc init = g1 (self loop)
__global__ void k_h1w1(const float* __restrict__ s0, const float* __restrict__ dinv,
                       const float* __restrict__ b0, const float* __restrict__ W1,
                       float* __restrict__ g1, float* __restrict__ outp, int N) {
    int i = blockIdx.x * 256 + threadIdx.x;
    if (i >= N) return;
    float dv = dinv[i];
    const float4* sp = (const float4*)(s0 + (size_t)i * HID);
    float4 a = sp[0], b = sp[1], c = sp[2], d = sp[3];
    float h[HID] = {a.x, a.y, a.z, a.w, b.x, b.y, b.z, b.w,
                    c.x, c.y, c.z, c.w, d.x, d.y, d.z, d.w};
#pragma unroll
    for (int j = 0; j < HID; ++j) h[j] = fmaxf(fmaf(h[j], dv, b0[j]), 0.f);
    float o[NC];
#pragma unroll
    for (int c2 = 0; c2 < NC; ++c2) o[c2] = 0.f;
#pragma unroll
    for (int j = 0; j < HID; ++j)
#pragma unroll
        for (int c2 = 0; c2 < NC; ++c2)
            o[c2] = fmaf(h[j], W1[j * NC + c2], o[c2]);  // uniform -> s_load
#pragma unroll
    for (int c2 = 0; c2 < NC; ++c2) {
        float v = o[c2] * dv;
        g1[(size_t)i * NC + c2] = v;
        outp[(size_t)i * NC + c2] = v;
    }
}

// outp[dst] += g1[src]  (8 lanes per edge, lane 7 idle)
__global__ void k_scat1(const int* __restrict__ src, const int* __restrict__ dst,
                        const float* __restrict__ g1, float* __restrict__ outp, int E) {
    int t = blockIdx.x * 256 + threadIdx.x;
    int e = t >> 3;
    if (e >= E) return;
    int c = t & 7;
    if (c >= NC) return;
    atomicAdd(&outp[(size_t)dst[e] * NC + c], g1[(size_t)src[e] * NC + c]);
}

// outp = outp*dinv + b1
__global__ void k_final(float* __restrict__ outp, const float* __restrict__ dinv,
                        const float* __restrict__ b1, int total) {
    int t = blockIdx.x * 256 + threadIdx.x;
    if (t >= total) return;
    int i = t / NC;
    int c = t - i * NC;
    outp[t] = fmaf(outp[t], dinv[i], b1[c]);
}

extern "C" void kernel_launch(void* const* d_in, const int* in_sizes, int n_in,
                              void* d_out, int out_size, void* d_ws, size_t ws_size,
                              hipStream_t stream) {
    const float* x  = (const float*)d_in[0];
    const int*   ei = (const int*)d_in[1];
    const float* W0 = (const float*)d_in[2];
    const float* b0 = (const float*)d_in[3];
    const float* W1 = (const float*)d_in[4];
    const float* b1 = (const float*)d_in[5];
    float* outp = (float*)d_out;

    int N = in_sizes[0] / FIN;
    int E = in_sizes[1] / 2;
    const int* src = ei;
    const int* dst = ei + E;

    // ws layout (floats): dinv[N] | g0[16N] | s0[16N] | g1[7N] (deg reuses g1 region)
    float* ws   = (float*)d_ws;
    float* dinv = ws;
    float* g0   = ws + N;
    float* s0   = ws + (size_t)17 * N;
    float* g1   = ws + (size_t)33 * N;
    float* degf = g1;  // only live before g1 is written

    hipMemsetAsync(degf, 0, (size_t)N * sizeof(float), stream);
    k_deg<<<(E + 255) / 256, 256, 0, stream>>>(dst, degf, E);
    k_dinv<<<(N + 255) / 256, 256, 0, stream>>>(degf, dinv, N);
    k_xw0<<<(2 * N + 255) / 256, 256, 0, stream>>>(x, W0, dinv, g0, s0, N);
    k_scat0<<<(int)(((size_t)E * 16 + 255) / 256), 256, 0, stream>>>(src, dst, g0, s0, E);
    k_h1w1<<<(N + 255) / 256, 256, 0, stream>>>(s0, dinv, b0, W1, g1, outp, N);
    k_scat1<<<(int)(((size_t)E * 8 + 255) / 256), 256, 0, stream>>>(src, dst, g1, outp, E);
    k_final<<<(N * NC + 255) / 256, 256, 0, stream>>>(outp, dinv, b1, N * NC);
}